// Round 7
// baseline (122.650 us; speedup 1.0000x reference)
//
#include <hip/hip_runtime.h>

#define MASK_HW 28
#define OUT_W 512
#define N_INST 100

typedef __attribute__((ext_vector_type(4))) float f32x4;

// idx: f32x4 index in [0, 100*512*512/4). 65536 f4 per instance, 128 per row.
__device__ __forceinline__ f32x4 compute_f4(
    const float* __restrict__ masks,
    const float* __restrict__ boxes,
    int idx)
{
    const int n   = idx >> 16;
    const int row = (idx & 65535) >> 7;
    const int xq  = idx & 127;

    const float by0 = boxes[4 * n + 1];
    const float by1 = boxes[4 * n + 3] + 1e-5f;
    const float syf = 28.0f / (by1 - by0);
    const float ys  = ((float)row + 0.5f - by0) * syf - 0.5f;

    f32x4 v = (f32x4)0.0f;
    if (ys > -1.0f && ys < 28.0f) {          // wave-uniform (row uniform per wave)
        const float bx0 = boxes[4 * n + 0];
        const float bx1 = boxes[4 * n + 2] + 1e-5f;
        const float sxf = 28.0f / (bx1 - bx0);

        const float y0f = floorf(ys);
        const int   y0i = (int)y0f;          // [-1, 27]
        const float wy1 = ys - y0f;
        const float wy0 = 1.0f - wy1;
        const float wyA = (y0i >= 0)  ? wy0 : 0.0f;
        const float wyB = (y0i <= 26) ? wy1 : 0.0f;
        const int   yA  = max(y0i, 0);
        const int   yB  = min(y0i + 1, MASK_HW - 1);
        const float* mrowA = masks + (size_t)n * (MASK_HW * MASK_HW) + yA * MASK_HW;
        const float* mrowB = masks + (size_t)n * (MASK_HW * MASK_HW) + yB * MASK_HW;

        const float xbase = (float)(xq * 4) + 0.5f - bx0;
        #pragma unroll
        for (int j = 0; j < 4; ++j) {
            const float xs = (xbase + (float)j) * sxf - 0.5f;
            float r = 0.0f;
            if (xs > -1.0f && xs < 28.0f) {
                const float x0f = floorf(xs);
                const int   x0i = (int)x0f;  // [-1, 27]
                const float wx1 = xs - x0f;
                const float wx0 = 1.0f - wx1;
                const float wxA = (x0i >= 0)  ? wx0 : 0.0f;
                const float wxB = (x0i <= 26) ? wx1 : 0.0f;
                const int   xA  = max(x0i, 0);
                const int   xB  = min(x0i + 1, MASK_HW - 1);
                r = wyA * (wxA * mrowA[xA] + wxB * mrowA[xB]) +
                    wyB * (wxA * mrowB[xA] + wxB * mrowB[xB]);
            }
            v[j] = r;
        }
    }
    return v;
}

// Fill-shaped: 2048 blocks x 256 threads, grid-stride with 4 independent
// stores in flight per step. Total 6,553,600 f4 = 12.5 per thread.
__global__ __launch_bounds__(256) void fused_paste_kernel(
    const float* __restrict__ masks,   // [N,1,28,28]
    const float* __restrict__ boxes,   // [N,4]
    f32x4* __restrict__ out)           // [N,512,512/4]
{
    const int gid = blockIdx.x * 256 + threadIdx.x;   // 0 .. 524287
    const int S   = 2048 * 256;                        // 524288

    int i = gid;
    for (int g = 0; g < 3; ++g) {                     // 12 full strided f4s
        f32x4 v0 = compute_f4(masks, boxes, i);
        f32x4 v1 = compute_f4(masks, boxes, i + S);
        f32x4 v2 = compute_f4(masks, boxes, i + 2 * S);
        f32x4 v3 = compute_f4(masks, boxes, i + 3 * S);
        out[i]         = v0;
        out[i + S]     = v1;
        out[i + 2 * S] = v2;
        out[i + 3 * S] = v3;
        i += 4 * S;
    }
    if (gid < 262144)                                  // 6,553,600 - 12*524,288
        out[i] = compute_f4(masks, boxes, i);
}

extern "C" void kernel_launch(void* const* d_in, const int* in_sizes, int n_in,
                              void* d_out, int out_size, void* d_ws, size_t ws_size,
                              hipStream_t stream) {
    const float* masks = (const float*)d_in[0];   // [100,1,28,28] fp32
    const float* boxes = (const float*)d_in[1];   // [100,4] fp32

    fused_paste_kernel<<<dim3(2048), dim3(256), 0, stream>>>(
        masks, boxes, (f32x4*)d_out);
}